// Round 4
// baseline (581.699 us; speedup 1.0000x reference)
//
#include <hip/hip_runtime.h>
#include <hip/hip_bf16.h>
#include <hip/hip_fp16.h>

#define N_NODES 100000
#define N_EDGES 1600000
#define ETOT    (N_EDGES + N_NODES)   // 1,700,000
#define NE3     (3 * ETOT)            // 5,100,000
#define N3      (3 * N_NODES)         // 300,000
#define NF      256
#define NG      512
#define NHC     64
#define NOUT3   192
#define BN_EPS  1e-5f

// bucket sort params: 512-node buckets
#define NBUCK   586                   // ceil(300000/512)
#define NB1     1024                  // level-1 blocks
#define EGRAIN  20
#define ECHUNK  (256 * EGRAIN)        // 5120
#define SCAN_N  (NBUCK * NB1)         // 600064

typedef _Float16 f16x8 __attribute__((ext_vector_type(8)));
typedef float    f32x4 __attribute__((ext_vector_type(4)));

__device__ __forceinline__ unsigned fenc(float f){
  unsigned b = __float_as_uint(f);
  return (b & 0x80000000u) ? ~b : (b | 0x80000000u);
}
__device__ __forceinline__ float fdec(unsigned u){
  unsigned b = (u & 0x80000000u) ? (u & 0x7FFFFFFFu) : ~u;
  return __uint_as_float(b);
}
__device__ __forceinline__ float lrelu(float x){ return x > 0.f ? x : 0.2f * x; }
__device__ __forceinline__ float eluf(float x){ return x > 0.f ? x : (__expf(x) - 1.f); }

// ---------------- init pooled (+amax tail) to encoded -inf ----------------
__global__ void k_init_pooled(unsigned* pooled){
  int i = blockIdx.x * 256 + threadIdx.x;
  if (i < 3 * NG * NHC + 6) pooled[i] = 0x007FFFFFu;   // fenc(-inf)
}

// ---------------- fused: column stats of x + level-1 edge histogram ----------------
#define STATS_NB ((N_NODES + 127) / 128)    // 782
__global__ __launch_bounds__(256) void k_pre(const float* __restrict__ x,
                                             float* __restrict__ sums, float* __restrict__ sumsq,
                                             const int* __restrict__ eA, const int* __restrict__ eC,
                                             const int* __restrict__ eP,
                                             int* __restrict__ gcounts){
  int t = threadIdx.x;
  if (blockIdx.x < STATS_NB){
    int r0 = blockIdx.x * 128;
    int rmax = N_NODES - r0; if (rmax > 128) rmax = 128;
    float s = 0.f, q = 0.f;
    for (int r = 0; r < rmax; ++r){
      float v = x[(size_t)(r0 + r) * NF + t];
      s += v; q += v * v;
    }
    atomicAdd(&sums[t], s);
    atomicAdd(&sumsq[t], q);
    return;
  }
  __shared__ int hist[NBUCK];
  int bi = blockIdx.x - STATS_NB;
  for (int b = t; b < NBUCK; b += 256) hist[b] = 0;
  __syncthreads();
  int base = bi * ECHUNK + t;
#pragma unroll
  for (int k = 0; k < EGRAIN; ++k){
    int i = base + k * 256;
    if (i < NE3){
      int v = i / ETOT; int j = i - v * ETOT;
      const int* ei = (v == 0) ? eA : (v == 1) ? eC : eP;
      int d = (j < N_EDGES) ? ei[N_EDGES + j] : (j - N_EDGES);
      int vd = v * N_NODES + d;
      atomicAdd(&hist[vd >> 9], 1);
    }
  }
  __syncthreads();
  for (int b = t; b < NBUCK; b += 256) gcounts[b * NB1 + bi] = hist[b];
}

// ---------------- fold BN into W'^T (fp16, [192][256]) and bias b' ----------------
__global__ __launch_bounds__(256) void k_prep2(const float* __restrict__ sums, const float* __restrict__ sumsq,
                                               const float* __restrict__ bn_w, const float* __restrict__ bn_b,
                                               const float* __restrict__ WA, const float* __restrict__ WC,
                                               const float* __restrict__ WP,
                                               __half* __restrict__ WpT, float* __restrict__ bp){
  __shared__ float red[256];
  int o = blockIdx.x;                 // 0..191
  int v = o >> 6, oc = o & 63;
  const float* W = (v == 0) ? WA : (v == 1) ? WC : WP;
  int f = threadIdx.x;
  float mu  = sums[f]  * (1.f / N_NODES);
  float var = sumsq[f] * (1.f / N_NODES) - mu * mu;
  float sc  = bn_w[f] * rsqrtf(var + BN_EPS);
  float sh_ = bn_b[f] - mu * sc;
  float w = W[f * 64 + oc];
  WpT[(size_t)o * NF + f] = __float2half(w * sc);
  red[f] = sh_ * w;
  __syncthreads();
  for (int off = 128; off > 0; off >>= 1){
    if (f < off) red[f] += red[f + off];
    __syncthreads();
  }
  if (f == 0) bp[o] = red[0];
}

// ---------------- exclusive scan (grain 8, 3 phases) ----------------
__global__ __launch_bounds__(256) void k_scan1(const int* __restrict__ cnt, int* __restrict__ out,
                                               int* __restrict__ bsum, int n){
  __shared__ int sh[256];
  int t = threadIdx.x; int base = blockIdx.x * 2048 + t * 8;
  int v[8]; int s = 0;
#pragma unroll
  for (int i = 0; i < 8; ++i){ v[i] = (base + i < n) ? cnt[base + i] : 0; s += v[i]; }
  sh[t] = s; __syncthreads();
  for (int off = 1; off < 256; off <<= 1){
    int xv = (t >= off) ? sh[t - off] : 0;
    __syncthreads();
    sh[t] += xv;
    __syncthreads();
  }
  int p = sh[t] - s;
  if (t == 255) bsum[blockIdx.x] = sh[255];
#pragma unroll
  for (int i = 0; i < 8; ++i){ if (base + i < n) out[base + i] = p; p += v[i]; }
}

__global__ __launch_bounds__(512) void k_scan2(int* __restrict__ bsum, int* __restrict__ total_out, int nb){
  __shared__ int sh[512];
  int t = threadIdx.x;
  int o = (t < nb) ? bsum[t] : 0;
  sh[t] = o; __syncthreads();
  for (int off = 1; off < 512; off <<= 1){
    int xv = (t >= off) ? sh[t - off] : 0;
    __syncthreads();
    sh[t] += xv;
    __syncthreads();
  }
  if (t < nb) bsum[t] = sh[t] - o;
  if (t == nb - 1) total_out[0] = sh[t];
}

__global__ __launch_bounds__(256) void k_scan3(int* __restrict__ out, const int* __restrict__ bsum, int n){
  int add = bsum[blockIdx.x];
  int base = blockIdx.x * 2048 + threadIdx.x * 8;
#pragma unroll
  for (int i = 0; i < 8; ++i) if (base + i < n) out[base + i] += add;
}

// ---------------- fused: MFMA fp16 GEMM + level-1 scatter ----------------
#define GBM 64
#define GEMM_NB ((N_NODES + GBM - 1) / GBM)   // 1563
__global__ __launch_bounds__(256) void k_fused(const float* __restrict__ x,
                                               const __half* __restrict__ WpT, const float* __restrict__ bp,
                                               __half* __restrict__ h16,
                                               const int* __restrict__ eA, const int* __restrict__ eC,
                                               const int* __restrict__ eP,
                                               const int* __restrict__ gscan, int* __restrict__ packed){
  union U { _Float16 xs[64 * 256]; int pos[NBUCK]; };
  __shared__ U sm;
  int t = threadIdx.x;
  if (blockIdx.x >= GEMM_NB){
    // -------- scatter path: LDS cursors, no global atomics --------
    int bi = blockIdx.x - GEMM_NB;
    for (int b = t; b < NBUCK; b += 256) sm.pos[b] = gscan[b * NB1 + bi];
    __syncthreads();
    int base = bi * ECHUNK + t;
#pragma unroll
    for (int k = 0; k < EGRAIN; ++k){
      int i = base + k * 256;
      if (i < NE3){
        int v = i / ETOT; int j = i - v * ETOT;
        const int* ei = (v == 0) ? eA : (v == 1) ? eC : eP;
        int s, d;
        if (j < N_EDGES){ s = ei[j]; d = ei[N_EDGES + j]; } else { s = j - N_EDGES; d = s; }
        int vd = v * N_NODES + d;
        int p = atomicAdd(&sm.pos[vd >> 9], 1);
        packed[p] = s | ((vd & 511) << 17);
      }
    }
    return;
  }
  // -------- MFMA GEMM path: tile 64 x 192, K=256 --------
  int m0 = blockIdx.x * GBM;
  // stage x rows -> LDS fp16, XOR-swizzled on 16B granules (read-conflict-free)
#pragma unroll
  for (int k = 0; k < 8; ++k){
    int G = t + k * 256;            // granule id 0..2047 (16B each)
    int row = G >> 5, g = G & 31;
    int grow = m0 + row; if (grow >= N_NODES) grow = N_NODES - 1;
    const float4* src = (const float4*)(x + (size_t)grow * NF + ((g ^ (row & 7)) << 3));
    float4 lo = src[0], hi = src[1];
    f16x8 h;
    h[0]=(_Float16)lo.x; h[1]=(_Float16)lo.y; h[2]=(_Float16)lo.z; h[3]=(_Float16)lo.w;
    h[4]=(_Float16)hi.x; h[5]=(_Float16)hi.y; h[6]=(_Float16)hi.z; h[7]=(_Float16)hi.w;
    *(f16x8*)&sm.xs[(size_t)G << 3] = h;
  }
  __syncthreads();
  int lane = t & 63, w = t >> 6;
  int lr = lane & 15, lk = lane >> 4;
  int colb = w * 48;                  // wave's 48 output cols
  f32x4 acc[4][3];
#pragma unroll
  for (int mt = 0; mt < 4; ++mt)
#pragma unroll
    for (int ct = 0; ct < 3; ++ct) acc[mt][ct] = (f32x4){0.f, 0.f, 0.f, 0.f};
  float bpv[3];
#pragma unroll
  for (int ct = 0; ct < 3; ++ct) bpv[ct] = bp[colb + ct * 16 + lr];
#pragma unroll
  for (int kk = 0; kk < 8; ++kk){
    int khalf = kk * 32 + lk * 8;
    f16x8 av[4];
#pragma unroll
    for (int mt = 0; mt < 4; ++mt){
      int row = mt * 16 + lr;
      av[mt] = *(const f16x8*)&sm.xs[row * 256 + (khalf ^ ((row & 7) << 3))];
    }
    f16x8 bv[3];
#pragma unroll
    for (int ct = 0; ct < 3; ++ct){
      int col = colb + ct * 16 + lr;
      bv[ct] = *(const f16x8*)(const void*)(WpT + (size_t)col * NF + khalf);
    }
#pragma unroll
    for (int mt = 0; mt < 4; ++mt)
#pragma unroll
      for (int ct = 0; ct < 3; ++ct)
        acc[mt][ct] = __builtin_amdgcn_mfma_f32_16x16x32_f16(av[mt], bv[ct], acc[mt][ct], 0, 0, 0);
  }
  // epilogue: C layout col=lane&15, row=(lane>>4)*4+reg
#pragma unroll
  for (int mt = 0; mt < 4; ++mt){
#pragma unroll
    for (int r = 0; r < 4; ++r){
      int row = m0 + mt * 16 + lk * 4 + r;
      if (row < N_NODES){
#pragma unroll
        for (int ct = 0; ct < 3; ++ct)
          h16[(size_t)row * NOUT3 + colb + ct * 16 + lr] = __float2half(acc[mt][ct][r] + bpv[ct]);
      }
    }
  }
}

// ---------------- level-2: per-bucket exact CSR build (LDS only) ----------------
__global__ __launch_bounds__(256) void k_build(const int* __restrict__ gscan, const int* __restrict__ packed,
                                               int* __restrict__ entries, int* __restrict__ offsets){
  __shared__ int hist2[512];
  __shared__ int sh[256];
  int b = blockIdx.x, t = threadIdx.x;
  int base = gscan[b * NB1];
  int end  = (b == NBUCK - 1) ? NE3 : gscan[(b + 1) * NB1];
  hist2[t * 2] = 0; hist2[t * 2 + 1] = 0;
  __syncthreads();
  for (int i = base + t; i < end; i += 256)
    atomicAdd(&hist2[(packed[i] >> 17) & 511], 1);
  __syncthreads();
  int s0 = hist2[t * 2], s1 = hist2[t * 2 + 1];
  int tot = s0 + s1;
  sh[t] = tot; __syncthreads();
  for (int off = 1; off < 256; off <<= 1){
    int xv = (t >= off) ? sh[t - off] : 0;
    __syncthreads();
    sh[t] += xv;
    __syncthreads();
  }
  int p = sh[t] - tot;
  hist2[t * 2]     = p;
  hist2[t * 2 + 1] = p + s0;
  __syncthreads();
#pragma unroll
  for (int i = 0; i < 2; ++i){
    int vd = (b << 9) + t * 2 + i;
    if (vd < N3) offsets[vd] = base + hist2[t * 2 + i];
  }
  if (b == NBUCK - 1 && t == 0) offsets[N3] = NE3;
  __syncthreads();
  for (int i = base + t; i < end; i += 256){
    int pk = packed[i];
    int low = (pk >> 17) & 511;
    int pos = atomicAdd(&hist2[low], 1);
    entries[base + pos] = pk & 0x1FFFF;
  }
}

// ---------------- attention logits + global per-(view,head) src-max ----------------
__global__ __launch_bounds__(256) void k_att(const __half* __restrict__ h16,
                                             const float* __restrict__ asA, const float* __restrict__ adA,
                                             const float* __restrict__ asC, const float* __restrict__ adC,
                                             const float* __restrict__ asP, const float* __restrict__ adP,
                                             float* __restrict__ a_src, float* __restrict__ a_dst,
                                             unsigned* __restrict__ amax){
  __shared__ unsigned samax[6];
  int t = threadIdx.x;
  if (t < 6) samax[t] = 0u;
  __syncthreads();
  int gt = blockIdx.x * 256 + t;
  int g = gt >> 4; int lid = gt & 15;          // grid exact: g < N3 always
  int v = g / N_NODES; int n = g - v * N_NODES;
  const float* As = (v == 0) ? asA : (v == 1) ? asC : asP;
  const float* Ad = (v == 0) ? adA : (v == 1) ? adC : adP;
  const __half2* hp = (const __half2*)(h16 + (size_t)n * NOUT3 + v * 64 + lid * 4);
  float2 fa = __half22float2(hp[0]);
  float2 fb = __half22float2(hp[1]);
  float4 s4 = *(const float4*)(As + lid * 4);
  float4 d4 = *(const float4*)(Ad + lid * 4);
  float rs = fa.x*s4.x + fa.y*s4.y + fb.x*s4.z + fb.y*s4.w;
  float rd = fa.x*d4.x + fa.y*d4.y + fb.x*d4.z + fb.y*d4.w;
  rs += __shfl_xor(rs, 1); rd += __shfl_xor(rd, 1);
  rs += __shfl_xor(rs, 2); rd += __shfl_xor(rd, 2);
  rs += __shfl_xor(rs, 4); rd += __shfl_xor(rd, 4);
  if ((lid & 7) == 0){
    int h = lid >> 3;
    a_src[g * 2 + h] = rs;
    a_dst[g * 2 + h] = rd;
    atomicMax(&samax[v * 2 + h], fenc(rs));
  }
  __syncthreads();
  if (t < 6) atomicMax(&amax[t], samax[t]);
}

// ---------------- gather: single-pass softmax (global-shift) + elu + graph max-pool ----------------
__global__ __launch_bounds__(256) void k_gather(const int* __restrict__ entries, const int* __restrict__ offsets,
                                                const float* __restrict__ a_src, const float* __restrict__ a_dst,
                                                const unsigned* __restrict__ amax,
                                                const __half* __restrict__ h16,
                                                const float* __restrict__ bA, const float* __restrict__ bC,
                                                const float* __restrict__ bP,
                                                const int* __restrict__ batch, unsigned* __restrict__ pooled){
  __shared__ unsigned red[64];
  __shared__ int kmin, kmax;
  int t = threadIdx.x;
  if (t == 0){ kmin = 0x7FFFFFFF; kmax = -1; }
  if (t < 64) red[t] = 0u;
  __syncthreads();
  int grp = t >> 4;
  int lid = t & 15;
  int g = blockIdx.x * 16 + grp;        // grid exact
  int v = g / N_NODES; int n = g - v * N_NODES;
  int vN = v * N_NODES;
  float ad0 = a_dst[g*2+0], ad1 = a_dst[g*2+1];
  float m0 = lrelu(fdec(amax[v*2+0]) + ad0);   // >= max edge logit for this dst
  float m1 = lrelu(fdec(amax[v*2+1]) + ad1);
  int beg = offsets[g], end = offsets[g+1];
  int len = end - beg;
  float ax = 0.f, ay = 0.f, az = 0.f, aw = 0.f;
  float den0 = 0.f, den1 = 0.f;
  const __half* hbase = h16 + v * 64 + lid * 4;
  int idx = 0;
  for (; idx + 2 <= len; idx += 2){
    int s0 = entries[beg + idx], s1 = entries[beg + idx + 1];
    float2 ap0 = *(const float2*)(a_src + (size_t)(vN + s0) * 2);
    float2 ap1 = *(const float2*)(a_src + (size_t)(vN + s1) * 2);
    uint2 r0 = *(const uint2*)(hbase + (size_t)s0 * NOUT3);
    uint2 r1 = *(const uint2*)(hbase + (size_t)s1 * NOUT3);
    float p00 = __expf(lrelu(ap0.x + ad0) - m0), p01 = __expf(lrelu(ap0.y + ad1) - m1);
    float p10 = __expf(lrelu(ap1.x + ad0) - m0), p11 = __expf(lrelu(ap1.y + ad1) - m1);
    den0 += p00 + p10; den1 += p01 + p11;
    float pa = (lid < 8) ? p00 : p01;
    float pb = (lid < 8) ? p10 : p11;
    float2 f0a = __half22float2(*(__half2*)&r0.x), f0b = __half22float2(*(__half2*)&r0.y);
    float2 f1a = __half22float2(*(__half2*)&r1.x), f1b = __half22float2(*(__half2*)&r1.y);
    ax += pa * f0a.x + pb * f1a.x; ay += pa * f0a.y + pb * f1a.y;
    az += pa * f0b.x + pb * f1b.x; aw += pa * f0b.y + pb * f1b.y;
  }
  if (idx < len){
    int s0 = entries[beg + idx];
    float2 ap0 = *(const float2*)(a_src + (size_t)(vN + s0) * 2);
    uint2 r0 = *(const uint2*)(hbase + (size_t)s0 * NOUT3);
    float p00 = __expf(lrelu(ap0.x + ad0) - m0), p01 = __expf(lrelu(ap0.y + ad1) - m1);
    den0 += p00; den1 += p01;
    float pa = (lid < 8) ? p00 : p01;
    float2 f0a = __half22float2(*(__half2*)&r0.x), f0b = __half22float2(*(__half2*)&r0.y);
    ax += pa * f0a.x; ay += pa * f0a.y; az += pa * f0b.x; aw += pa * f0b.y;
  }
  float den = ((lid < 8) ? den0 : den1) + 1e-16f;
  const float* bias = (v == 0) ? bA : (v == 1) ? bC : bP;
  float4 b4 = *(const float4*)(bias + lid * 4);
  unsigned e0u = fenc(eluf(ax / den + b4.x));
  unsigned e1u = fenc(eluf(ay / den + b4.y));
  unsigned e2u = fenc(eluf(az / den + b4.z));
  unsigned e3u = fenc(eluf(aw / den + b4.w));
  int key = v * NG + batch[n];
  if (lid == 0){ atomicMin(&kmin, key); atomicMax(&kmax, key); }
  atomicMax(&red[lid*4+0], e0u); atomicMax(&red[lid*4+1], e1u);
  atomicMax(&red[lid*4+2], e2u); atomicMax(&red[lid*4+3], e3u);
  __syncthreads();
  if (kmin == kmax){
    if (t < 64) atomicMax(&pooled[(size_t)kmin * 64 + t], red[t]);
  } else {
    unsigned* pp = pooled + (size_t)key * 64 + lid * 4;
    atomicMax(pp+0, e0u); atomicMax(pp+1, e1u); atomicMax(pp+2, e2u); atomicMax(pp+3, e3u);
  }
}

// ---------------- head MLP: one wave per graph ----------------
__global__ __launch_bounds__(64) void k_head(const unsigned* __restrict__ pooled,
                                             const float* __restrict__ g1w, const float* __restrict__ g1b,
                                             const float* __restrict__ g2w, const float* __restrict__ g2b,
                                             const float* __restrict__ c1w, const float* __restrict__ c1b,
                                             const float* __restrict__ c2w, const float* __restrict__ c2b,
                                             const float* __restrict__ c3w, const float* __restrict__ c3b,
                                             float* __restrict__ out){
  __shared__ float s1[64];
  __shared__ float s2[128];
  __shared__ float sw[3];
  int g = blockIdx.x, l = threadIdx.x;
  float ha = fdec(pooled[(size_t)g * 64 + l]);
  float hc = fdec(pooled[(size_t)(NG + g) * 64 + l]);
  float hp = fdec(pooled[(size_t)(2 * NG + g) * 64 + l]);
  s1[l] = (ha + hc + hp) * (1.f / 3.f);
  __syncthreads();
  float r1 = 0.f;
  if (l < 32){
    r1 = g1b[l];
    for (int i = 0; i < 64; ++i) r1 += s1[i] * g1w[i * 32 + l];
    r1 = fmaxf(r1, 0.f);
  }
  __syncthreads();
  if (l < 32) s2[l] = r1;
  __syncthreads();
  if (l < 3){
    float tv = g2b[l];
    for (int i = 0; i < 32; ++i) tv += s2[i] * g2w[i * 3 + l];
    sw[l] = tv;
  }
  __syncthreads();
  float t0 = sw[0], t1 = sw[1], t2 = sw[2];
  float mx = fmaxf(t0, fmaxf(t1, t2));
  float w0 = __expf(t0 - mx), w1 = __expf(t1 - mx), w2 = __expf(t2 - mx);
  float wsum = w0 + w1 + w2;
  float fused = (w0 * ha + w1 * hc + w2 * hp) / wsum;
  __syncthreads();
  s1[l] = fused;
  __syncthreads();
  float za = c1b[l], zb = c1b[64 + l];
  for (int i = 0; i < 64; ++i){
    float f = s1[i];
    za += f * c1w[i * 128 + l];
    zb += f * c1w[i * 128 + 64 + l];
  }
  za = fmaxf(za, 0.f); zb = fmaxf(zb, 0.f);
  s2[l] = za; s2[64 + l] = zb;
  __syncthreads();
  float z2 = c2b[l];
  for (int i = 0; i < 128; ++i) z2 += s2[i] * c2w[i * 64 + l];
  z2 = fmaxf(z2, 0.f);
  float prod = z2 * c3w[l];
  for (int off = 32; off > 0; off >>= 1) prod += __shfl_down(prod, off);
  if (l == 0) out[g] = prod + c3b[0];
}

extern "C" void kernel_launch(void* const* d_in, const int* in_sizes, int n_in,
                              void* d_out, int out_size, void* d_ws, size_t ws_size,
                              hipStream_t stream){
  const float* x    = (const float*)d_in[0];
  const int* eA     = (const int*)d_in[1];
  const int* eC     = (const int*)d_in[2];
  const int* eP     = (const int*)d_in[3];
  const int* batch  = (const int*)d_in[4];
  const float* bn_w = (const float*)d_in[6];
  const float* bn_b = (const float*)d_in[7];
  const float* WA   = (const float*)d_in[8];
  const float* asA  = (const float*)d_in[9];
  const float* adA  = (const float*)d_in[10];
  const float* bA   = (const float*)d_in[11];
  const float* WC   = (const float*)d_in[12];
  const float* asC  = (const float*)d_in[13];
  const float* adC  = (const float*)d_in[14];
  const float* bC   = (const float*)d_in[15];
  const float* WP   = (const float*)d_in[16];
  const float* asP  = (const float*)d_in[17];
  const float* adP  = (const float*)d_in[18];
  const float* bP   = (const float*)d_in[19];
  const float* g1w  = (const float*)d_in[20];
  const float* g1b  = (const float*)d_in[21];
  const float* g2w  = (const float*)d_in[22];
  const float* g2b  = (const float*)d_in[23];
  const float* c1w  = (const float*)d_in[24];
  const float* c1b  = (const float*)d_in[25];
  const float* c2w  = (const float*)d_in[26];
  const float* c2b  = (const float*)d_in[27];
  const float* c3w  = (const float*)d_in[28];
  const float* c3b  = (const float*)d_in[29];
  float* out = (float*)d_out;

  char* wptr = (char*)d_ws;
  auto alloc = [&](size_t bytes) -> void* {
    void* p = (void*)wptr;
    wptr += (bytes + 255) & ~(size_t)255;
    return p;
  };
  float*    sums    = (float*)   alloc((size_t)NF * 4);
  float*    sumsq   = (float*)   alloc((size_t)NF * 4);
  size_t zbytes = (size_t)(wptr - (char*)sums);
  int*      gcounts = (int*)     alloc((size_t)SCAN_N * 4);
  int*      gscan   = (int*)     alloc((size_t)SCAN_N * 4);
  int*      offsets = (int*)     alloc(((size_t)N3 + 1) * 4);
  __half*   WpT     = (__half*)  alloc((size_t)NOUT3 * NF * 2);
  float*    bp      = (float*)   alloc((size_t)NOUT3 * 4);
  __half*   h16     = (__half*)  alloc((size_t)N_NODES * NOUT3 * 2);
  float*    a_src   = (float*)   alloc((size_t)N3 * 2 * 4);
  float*    a_dst   = (float*)   alloc((size_t)N3 * 2 * 4);
  int*      packed  = (int*)     alloc((size_t)NE3 * 4);
  int*      entries = (int*)     alloc((size_t)NE3 * 4);
  unsigned* pooled  = (unsigned*)alloc(((size_t)3 * NG * NHC + 6) * 4);
  int*      bsum    = (int*)     alloc((size_t)512 * 4);
  int*      scrtot  = (int*)     alloc((size_t)64 * 4);
  unsigned* amax    = pooled + (size_t)3 * NG * NHC;

  hipMemsetAsync(sums, 0, zbytes, stream);
  k_init_pooled<<<(3 * NG * NHC + 6 + 255) / 256, 256, 0, stream>>>(pooled);
  k_pre<<<STATS_NB + NB1, 256, 0, stream>>>(x, sums, sumsq, eA, eC, eP, gcounts);
  k_prep2<<<NOUT3, 256, 0, stream>>>(sums, sumsq, bn_w, bn_b, WA, WC, WP, WpT, bp);
  int nb_sc = (SCAN_N + 2047) / 2048;   // 293
  k_scan1<<<nb_sc, 256, 0, stream>>>(gcounts, gscan, bsum, SCAN_N);
  k_scan2<<<1, 512, 0, stream>>>(bsum, scrtot, nb_sc);
  k_scan3<<<nb_sc, 256, 0, stream>>>(gscan, bsum, SCAN_N);
  k_fused<<<GEMM_NB + NB1, 256, 0, stream>>>(x, WpT, bp, h16, eA, eC, eP, gscan, packed);
  k_att<<<N3 * 16 / 256, 256, 0, stream>>>(h16, asA, adA, asC, adC, asP, adP, a_src, a_dst, amax);
  k_build<<<NBUCK, 256, 0, stream>>>(gscan, packed, entries, offsets);
  k_gather<<<N3 / 16, 256, 0, stream>>>(entries, offsets, a_src, a_dst, amax, h16, bA, bC, bP, batch, pooled);
  k_head<<<NG, 64, 0, stream>>>(pooled, g1w, g1b, g2w, g2b, c1w, c1b, c2w, c2b, c3w, c3b, out);
}

// Round 5
// 409.036 us; speedup vs baseline: 1.4221x; 1.4221x over previous
//
#include <hip/hip_runtime.h>
#include <hip/hip_bf16.h>
#include <hip/hip_fp16.h>

#define N_NODES 100000
#define N_EDGES 1600000
#define ETOT    (N_EDGES + N_NODES)   // 1,700,000
#define NE3     (3 * ETOT)            // 5,100,000
#define N3      (3 * N_NODES)         // 300,000
#define NF      256
#define NG      512
#define NHC     64
#define NOUT3   192
#define BN_EPS  1e-5f

// bucket sort params: 512-node buckets
#define NBUCK   586                   // ceil(300000/512)
#define NB1     1024                  // level-1 blocks
#define EGRAIN  20
#define ECHUNK  (256 * EGRAIN)        // 5120
#define SCAN_N  (NBUCK * NB1)         // 600064
#define ATT_NB  (N3 * 16 / 256)       // 18750

typedef _Float16 f16x8 __attribute__((ext_vector_type(8)));
typedef float    f32x4 __attribute__((ext_vector_type(4)));

__device__ __forceinline__ unsigned fenc(float f){
  unsigned b = __float_as_uint(f);
  return (b & 0x80000000u) ? ~b : (b | 0x80000000u);
}
__device__ __forceinline__ float fdec(unsigned u){
  unsigned b = (u & 0x80000000u) ? (u & 0x7FFFFFFFu) : ~u;
  return __uint_as_float(b);
}
__device__ __forceinline__ float lrelu(float x){ return x > 0.f ? x : 0.2f * x; }
__device__ __forceinline__ float eluf(float x){ return x > 0.f ? x : (__expf(x) - 1.f); }

// ---------------- init pooled to encoded -inf ----------------
__global__ void k_init_pooled(unsigned* pooled){
  int i = blockIdx.x * 256 + threadIdx.x;
  if (i < 3 * NG * NHC) pooled[i] = 0x007FFFFFu;   // fenc(-inf)
}

// ---------------- fused: column stats of x + level-1 edge histogram ----------------
#define STATS_NB ((N_NODES + 127) / 128)    // 782
__global__ __launch_bounds__(256) void k_pre(const float* __restrict__ x,
                                             float* __restrict__ sums, float* __restrict__ sumsq,
                                             const int* __restrict__ eA, const int* __restrict__ eC,
                                             const int* __restrict__ eP,
                                             int* __restrict__ gcounts){
  int t = threadIdx.x;
  if (blockIdx.x < STATS_NB){
    int r0 = blockIdx.x * 128;
    int rmax = N_NODES - r0; if (rmax > 128) rmax = 128;
    float s = 0.f, q = 0.f;
    for (int r = 0; r < rmax; ++r){
      float v = x[(size_t)(r0 + r) * NF + t];
      s += v; q += v * v;
    }
    atomicAdd(&sums[t], s);
    atomicAdd(&sumsq[t], q);
    return;
  }
  __shared__ int hist[NBUCK];
  int bi = blockIdx.x - STATS_NB;
  for (int b = t; b < NBUCK; b += 256) hist[b] = 0;
  __syncthreads();
  int base = bi * ECHUNK + t;
#pragma unroll
  for (int k = 0; k < EGRAIN; ++k){
    int i = base + k * 256;
    if (i < NE3){
      int v = i / ETOT; int j = i - v * ETOT;
      const int* ei = (v == 0) ? eA : (v == 1) ? eC : eP;
      int d = (j < N_EDGES) ? ei[N_EDGES + j] : (j - N_EDGES);
      int vd = v * N_NODES + d;
      atomicAdd(&hist[vd >> 9], 1);
    }
  }
  __syncthreads();
  for (int b = t; b < NBUCK; b += 256) gcounts[b * NB1 + bi] = hist[b];
}

// ---------------- fold BN into W'^T (fp16, [192][256]) and bias b' ----------------
__global__ __launch_bounds__(256) void k_prep2(const float* __restrict__ sums, const float* __restrict__ sumsq,
                                               const float* __restrict__ bn_w, const float* __restrict__ bn_b,
                                               const float* __restrict__ WA, const float* __restrict__ WC,
                                               const float* __restrict__ WP,
                                               __half* __restrict__ WpT, float* __restrict__ bp){
  __shared__ float red[256];
  int o = blockIdx.x;                 // 0..191
  int v = o >> 6, oc = o & 63;
  const float* W = (v == 0) ? WA : (v == 1) ? WC : WP;
  int f = threadIdx.x;
  float mu  = sums[f]  * (1.f / N_NODES);
  float var = sumsq[f] * (1.f / N_NODES) - mu * mu;
  float sc  = bn_w[f] * rsqrtf(var + BN_EPS);
  float sh_ = bn_b[f] - mu * sc;
  float w = W[f * 64 + oc];
  WpT[(size_t)o * NF + f] = __float2half(w * sc);
  red[f] = sh_ * w;
  __syncthreads();
  for (int off = 128; off > 0; off >>= 1){
    if (f < off) red[f] += red[f + off];
    __syncthreads();
  }
  if (f == 0) bp[o] = red[0];
}

// ---------------- exclusive scan (grain 8, 3 phases) ----------------
__global__ __launch_bounds__(256) void k_scan1(const int* __restrict__ cnt, int* __restrict__ out,
                                               int* __restrict__ bsum, int n){
  __shared__ int sh[256];
  int t = threadIdx.x; int base = blockIdx.x * 2048 + t * 8;
  int v[8]; int s = 0;
#pragma unroll
  for (int i = 0; i < 8; ++i){ v[i] = (base + i < n) ? cnt[base + i] : 0; s += v[i]; }
  sh[t] = s; __syncthreads();
  for (int off = 1; off < 256; off <<= 1){
    int xv = (t >= off) ? sh[t - off] : 0;
    __syncthreads();
    sh[t] += xv;
    __syncthreads();
  }
  int p = sh[t] - s;
  if (t == 255) bsum[blockIdx.x] = sh[255];
#pragma unroll
  for (int i = 0; i < 8; ++i){ if (base + i < n) out[base + i] = p; p += v[i]; }
}

__global__ __launch_bounds__(512) void k_scan2(int* __restrict__ bsum, int* __restrict__ total_out, int nb){
  __shared__ int sh[512];
  int t = threadIdx.x;
  int o = (t < nb) ? bsum[t] : 0;
  sh[t] = o; __syncthreads();
  for (int off = 1; off < 512; off <<= 1){
    int xv = (t >= off) ? sh[t - off] : 0;
    __syncthreads();
    sh[t] += xv;
    __syncthreads();
  }
  if (t < nb) bsum[t] = sh[t] - o;
  if (t == nb - 1) total_out[0] = sh[t];
}

__global__ __launch_bounds__(256) void k_scan3(int* __restrict__ out, const int* __restrict__ bsum, int n){
  int add = bsum[blockIdx.x];
  int base = blockIdx.x * 2048 + threadIdx.x * 8;
#pragma unroll
  for (int i = 0; i < 8; ++i) if (base + i < n) out[base + i] += add;
}

// ---------------- fused: MFMA fp16 GEMM + level-1 scatter ----------------
#define GBM 64
#define GEMM_NB ((N_NODES + GBM - 1) / GBM)   // 1563
__global__ __launch_bounds__(256) void k_fused(const float* __restrict__ x,
                                               const __half* __restrict__ WpT, const float* __restrict__ bp,
                                               __half* __restrict__ h16,
                                               const int* __restrict__ eA, const int* __restrict__ eC,
                                               const int* __restrict__ eP,
                                               const int* __restrict__ gscan, int* __restrict__ packed){
  union U { _Float16 xs[64 * 256]; int pos[NBUCK]; };
  __shared__ U sm;
  int t = threadIdx.x;
  if (blockIdx.x >= GEMM_NB){
    // -------- scatter path: LDS cursors, no global atomics --------
    int bi = blockIdx.x - GEMM_NB;
    for (int b = t; b < NBUCK; b += 256) sm.pos[b] = gscan[b * NB1 + bi];
    __syncthreads();
    int base = bi * ECHUNK + t;
#pragma unroll
    for (int k = 0; k < EGRAIN; ++k){
      int i = base + k * 256;
      if (i < NE3){
        int v = i / ETOT; int j = i - v * ETOT;
        const int* ei = (v == 0) ? eA : (v == 1) ? eC : eP;
        int s, d;
        if (j < N_EDGES){ s = ei[j]; d = ei[N_EDGES + j]; } else { s = j - N_EDGES; d = s; }
        int vd = v * N_NODES + d;
        int p = atomicAdd(&sm.pos[vd >> 9], 1);
        packed[p] = s | ((vd & 511) << 17);
      }
    }
    return;
  }
  // -------- MFMA GEMM path: tile 64 x 192, K=256 --------
  int m0 = blockIdx.x * GBM;
#pragma unroll
  for (int k = 0; k < 8; ++k){
    int G = t + k * 256;            // granule id 0..2047 (16B each)
    int row = G >> 5, g = G & 31;
    int grow = m0 + row; if (grow >= N_NODES) grow = N_NODES - 1;
    const float4* src = (const float4*)(x + (size_t)grow * NF + ((g ^ (row & 7)) << 3));
    float4 lo = src[0], hi = src[1];
    f16x8 h;
    h[0]=(_Float16)lo.x; h[1]=(_Float16)lo.y; h[2]=(_Float16)lo.z; h[3]=(_Float16)lo.w;
    h[4]=(_Float16)hi.x; h[5]=(_Float16)hi.y; h[6]=(_Float16)hi.z; h[7]=(_Float16)hi.w;
    *(f16x8*)&sm.xs[(size_t)G << 3] = h;
  }
  __syncthreads();
  int lane = t & 63, w = t >> 6;
  int lr = lane & 15, lk = lane >> 4;
  int colb = w * 48;                  // wave's 48 output cols
  f32x4 acc[4][3];
#pragma unroll
  for (int mt = 0; mt < 4; ++mt)
#pragma unroll
    for (int ct = 0; ct < 3; ++ct) acc[mt][ct] = (f32x4){0.f, 0.f, 0.f, 0.f};
  float bpv[3];
#pragma unroll
  for (int ct = 0; ct < 3; ++ct) bpv[ct] = bp[colb + ct * 16 + lr];
#pragma unroll
  for (int kk = 0; kk < 8; ++kk){
    int khalf = kk * 32 + lk * 8;
    f16x8 av[4];
#pragma unroll
    for (int mt = 0; mt < 4; ++mt){
      int row = mt * 16 + lr;
      av[mt] = *(const f16x8*)&sm.xs[row * 256 + (khalf ^ ((row & 7) << 3))];
    }
    f16x8 bv[3];
#pragma unroll
    for (int ct = 0; ct < 3; ++ct){
      int col = colb + ct * 16 + lr;
      bv[ct] = *(const f16x8*)(const void*)(WpT + (size_t)col * NF + khalf);
    }
#pragma unroll
    for (int mt = 0; mt < 4; ++mt)
#pragma unroll
      for (int ct = 0; ct < 3; ++ct)
        acc[mt][ct] = __builtin_amdgcn_mfma_f32_16x16x32_f16(av[mt], bv[ct], acc[mt][ct], 0, 0, 0);
  }
  // epilogue: C layout col=lane&15, row=(lane>>4)*4+reg
#pragma unroll
  for (int mt = 0; mt < 4; ++mt){
#pragma unroll
    for (int r = 0; r < 4; ++r){
      int row = m0 + mt * 16 + lk * 4 + r;
      if (row < N_NODES){
#pragma unroll
        for (int ct = 0; ct < 3; ++ct)
          h16[(size_t)row * NOUT3 + colb + ct * 16 + lr] = __float2half(acc[mt][ct][r] + bpv[ct]);
      }
    }
  }
}

// ---------------- level-2: per-bucket exact CSR build (LDS only) ----------------
__global__ __launch_bounds__(256) void k_build(const int* __restrict__ gscan, const int* __restrict__ packed,
                                               int* __restrict__ entries, int* __restrict__ offsets){
  __shared__ int hist2[512];
  __shared__ int sh[256];
  int b = blockIdx.x, t = threadIdx.x;
  int base = gscan[b * NB1];
  int end  = (b == NBUCK - 1) ? NE3 : gscan[(b + 1) * NB1];
  hist2[t * 2] = 0; hist2[t * 2 + 1] = 0;
  __syncthreads();
  for (int i = base + t; i < end; i += 256)
    atomicAdd(&hist2[(packed[i] >> 17) & 511], 1);
  __syncthreads();
  int s0 = hist2[t * 2], s1 = hist2[t * 2 + 1];
  int tot = s0 + s1;
  sh[t] = tot; __syncthreads();
  for (int off = 1; off < 256; off <<= 1){
    int xv = (t >= off) ? sh[t - off] : 0;
    __syncthreads();
    sh[t] += xv;
    __syncthreads();
  }
  int p = sh[t] - tot;
  hist2[t * 2]     = p;
  hist2[t * 2 + 1] = p + s0;
  __syncthreads();
#pragma unroll
  for (int i = 0; i < 2; ++i){
    int vd = (b << 9) + t * 2 + i;
    if (vd < N3) offsets[vd] = base + hist2[t * 2 + i];
  }
  if (b == NBUCK - 1 && t == 0) offsets[N3] = NE3;
  __syncthreads();
  for (int i = base + t; i < end; i += 256){
    int pk = packed[i];
    int low = (pk >> 17) & 511;
    int pos = atomicAdd(&hist2[low], 1);
    entries[base + pos] = pk & 0x1FFFF;
  }
}

// ---------------- attention logits + per-block partial src-max (plain stores) ----------------
__global__ __launch_bounds__(256) void k_att(const __half* __restrict__ h16,
                                             const float* __restrict__ asA, const float* __restrict__ adA,
                                             const float* __restrict__ asC, const float* __restrict__ adC,
                                             const float* __restrict__ asP, const float* __restrict__ adP,
                                             float* __restrict__ a_src, float* __restrict__ a_dst,
                                             unsigned* __restrict__ gpart){
  __shared__ unsigned samax[6];
  int t = threadIdx.x;
  if (t < 6) samax[t] = 0u;
  __syncthreads();
  int gt = blockIdx.x * 256 + t;
  int g = gt >> 4; int lid = gt & 15;          // grid exact: g < N3 always
  int v = g / N_NODES; int n = g - v * N_NODES;
  const float* As = (v == 0) ? asA : (v == 1) ? asC : asP;
  const float* Ad = (v == 0) ? adA : (v == 1) ? adC : adP;
  const __half2* hp = (const __half2*)(h16 + (size_t)n * NOUT3 + v * 64 + lid * 4);
  float2 fa = __half22float2(hp[0]);
  float2 fb = __half22float2(hp[1]);
  float4 s4 = *(const float4*)(As + lid * 4);
  float4 d4 = *(const float4*)(Ad + lid * 4);
  float rs = fa.x*s4.x + fa.y*s4.y + fb.x*s4.z + fb.y*s4.w;
  float rd = fa.x*d4.x + fa.y*d4.y + fb.x*d4.z + fb.y*d4.w;
  rs += __shfl_xor(rs, 1); rd += __shfl_xor(rd, 1);
  rs += __shfl_xor(rs, 2); rd += __shfl_xor(rd, 2);
  rs += __shfl_xor(rs, 4); rd += __shfl_xor(rd, 4);
  if ((lid & 7) == 0){
    int h = lid >> 3;
    a_src[g * 2 + h] = rs;
    a_dst[g * 2 + h] = rd;
    atomicMax(&samax[v * 2 + h], fenc(rs));
  }
  __syncthreads();
  if (t < 6) gpart[blockIdx.x * 6 + t] = samax[t];   // plain store, no global atomic
}

// ---------------- reduce 18750x6 partials -> amax[6] ----------------
__global__ __launch_bounds__(256) void k_amax(const unsigned* __restrict__ gpart, unsigned* __restrict__ amax){
  __shared__ unsigned sm[6];
  int t = threadIdx.x;
  if (t < 6) sm[t] = 0u;
  __syncthreads();
  unsigned m[6] = {0u, 0u, 0u, 0u, 0u, 0u};
  for (int bi = t; bi < ATT_NB; bi += 256){
    const unsigned* p = gpart + (size_t)bi * 6;
#pragma unroll
    for (int k = 0; k < 6; ++k) m[k] = max(m[k], p[k]);
  }
#pragma unroll
  for (int k = 0; k < 6; ++k) atomicMax(&sm[k], m[k]);
  __syncthreads();
  if (t < 6) amax[t] = sm[t];
}

// ---------------- gather: single-pass softmax (global-shift) + elu + graph max-pool ----------------
__global__ __launch_bounds__(256) void k_gather(const int* __restrict__ entries, const int* __restrict__ offsets,
                                                const float* __restrict__ a_src, const float* __restrict__ a_dst,
                                                const unsigned* __restrict__ amax,
                                                const __half* __restrict__ h16,
                                                const float* __restrict__ bA, const float* __restrict__ bC,
                                                const float* __restrict__ bP,
                                                const int* __restrict__ batch, unsigned* __restrict__ pooled){
  __shared__ unsigned red[64];
  __shared__ int kmin, kmax;
  int t = threadIdx.x;
  if (t == 0){ kmin = 0x7FFFFFFF; kmax = -1; }
  if (t < 64) red[t] = 0u;
  __syncthreads();
  int grp = t >> 4;
  int lid = t & 15;
  int g = blockIdx.x * 16 + grp;        // grid exact
  int v = g / N_NODES; int n = g - v * N_NODES;
  int vN = v * N_NODES;
  float ad0 = a_dst[g*2+0], ad1 = a_dst[g*2+1];
  float m0 = lrelu(fdec(amax[v*2+0]) + ad0);   // >= max edge logit for this dst
  float m1 = lrelu(fdec(amax[v*2+1]) + ad1);
  int beg = offsets[g], end = offsets[g+1];
  int len = end - beg;
  float ax = 0.f, ay = 0.f, az = 0.f, aw = 0.f;
  float den0 = 0.f, den1 = 0.f;
  const __half* hbase = h16 + v * 64 + lid * 4;
  int idx = 0;
  for (; idx + 2 <= len; idx += 2){
    int s0 = entries[beg + idx], s1 = entries[beg + idx + 1];
    float2 ap0 = *(const float2*)(a_src + (size_t)(vN + s0) * 2);
    float2 ap1 = *(const float2*)(a_src + (size_t)(vN + s1) * 2);
    uint2 r0 = *(const uint2*)(hbase + (size_t)s0 * NOUT3);
    uint2 r1 = *(const uint2*)(hbase + (size_t)s1 * NOUT3);
    float p00 = __expf(lrelu(ap0.x + ad0) - m0), p01 = __expf(lrelu(ap0.y + ad1) - m1);
    float p10 = __expf(lrelu(ap1.x + ad0) - m0), p11 = __expf(lrelu(ap1.y + ad1) - m1);
    den0 += p00 + p10; den1 += p01 + p11;
    float pa = (lid < 8) ? p00 : p01;
    float pb = (lid < 8) ? p10 : p11;
    float2 f0a = __half22float2(*(__half2*)&r0.x), f0b = __half22float2(*(__half2*)&r0.y);
    float2 f1a = __half22float2(*(__half2*)&r1.x), f1b = __half22float2(*(__half2*)&r1.y);
    ax += pa * f0a.x + pb * f1a.x; ay += pa * f0a.y + pb * f1a.y;
    az += pa * f0b.x + pb * f1b.x; aw += pa * f0b.y + pb * f1b.y;
  }
  if (idx < len){
    int s0 = entries[beg + idx];
    float2 ap0 = *(const float2*)(a_src + (size_t)(vN + s0) * 2);
    uint2 r0 = *(const uint2*)(hbase + (size_t)s0 * NOUT3);
    float p00 = __expf(lrelu(ap0.x + ad0) - m0), p01 = __expf(lrelu(ap0.y + ad1) - m1);
    den0 += p00; den1 += p01;
    float pa = (lid < 8) ? p00 : p01;
    float2 f0a = __half22float2(*(__half2*)&r0.x), f0b = __half22float2(*(__half2*)&r0.y);
    ax += pa * f0a.x; ay += pa * f0a.y; az += pa * f0b.x; aw += pa * f0b.y;
  }
  float den = ((lid < 8) ? den0 : den1) + 1e-16f;
  const float* bias = (v == 0) ? bA : (v == 1) ? bC : bP;
  float4 b4 = *(const float4*)(bias + lid * 4);
  unsigned e0u = fenc(eluf(ax / den + b4.x));
  unsigned e1u = fenc(eluf(ay / den + b4.y));
  unsigned e2u = fenc(eluf(az / den + b4.z));
  unsigned e3u = fenc(eluf(aw / den + b4.w));
  int key = v * NG + batch[n];
  if (lid == 0){ atomicMin(&kmin, key); atomicMax(&kmax, key); }
  atomicMax(&red[lid*4+0], e0u); atomicMax(&red[lid*4+1], e1u);
  atomicMax(&red[lid*4+2], e2u); atomicMax(&red[lid*4+3], e3u);
  __syncthreads();
  if (kmin == kmax){
    if (t < 64) atomicMax(&pooled[(size_t)kmin * 64 + t], red[t]);
  } else {
    unsigned* pp = pooled + (size_t)key * 64 + lid * 4;
    atomicMax(pp+0, e0u); atomicMax(pp+1, e1u); atomicMax(pp+2, e2u); atomicMax(pp+3, e3u);
  }
}

// ---------------- head MLP: one wave per graph ----------------
__global__ __launch_bounds__(64) void k_head(const unsigned* __restrict__ pooled,
                                             const float* __restrict__ g1w, const float* __restrict__ g1b,
                                             const float* __restrict__ g2w, const float* __restrict__ g2b,
                                             const float* __restrict__ c1w, const float* __restrict__ c1b,
                                             const float* __restrict__ c2w, const float* __restrict__ c2b,
                                             const float* __restrict__ c3w, const float* __restrict__ c3b,
                                             float* __restrict__ out){
  __shared__ float s1[64];
  __shared__ float s2[128];
  __shared__ float sw[3];
  int g = blockIdx.x, l = threadIdx.x;
  float ha = fdec(pooled[(size_t)g * 64 + l]);
  float hc = fdec(pooled[(size_t)(NG + g) * 64 + l]);
  float hp = fdec(pooled[(size_t)(2 * NG + g) * 64 + l]);
  s1[l] = (ha + hc + hp) * (1.f / 3.f);
  __syncthreads();
  float r1 = 0.f;
  if (l < 32){
    r1 = g1b[l];
    for (int i = 0; i < 64; ++i) r1 += s1[i] * g1w[i * 32 + l];
    r1 = fmaxf(r1, 0.f);
  }
  __syncthreads();
  if (l < 32) s2[l] = r1;
  __syncthreads();
  if (l < 3){
    float tv = g2b[l];
    for (int i = 0; i < 32; ++i) tv += s2[i] * g2w[i * 3 + l];
    sw[l] = tv;
  }
  __syncthreads();
  float t0 = sw[0], t1 = sw[1], t2 = sw[2];
  float mx = fmaxf(t0, fmaxf(t1, t2));
  float w0 = __expf(t0 - mx), w1 = __expf(t1 - mx), w2 = __expf(t2 - mx);
  float wsum = w0 + w1 + w2;
  float fused = (w0 * ha + w1 * hc + w2 * hp) / wsum;
  __syncthreads();
  s1[l] = fused;
  __syncthreads();
  float za = c1b[l], zb = c1b[64 + l];
  for (int i = 0; i < 64; ++i){
    float f = s1[i];
    za += f * c1w[i * 128 + l];
    zb += f * c1w[i * 128 + 64 + l];
  }
  za = fmaxf(za, 0.f); zb = fmaxf(zb, 0.f);
  s2[l] = za; s2[64 + l] = zb;
  __syncthreads();
  float z2 = c2b[l];
  for (int i = 0; i < 128; ++i) z2 += s2[i] * c2w[i * 64 + l];
  z2 = fmaxf(z2, 0.f);
  float prod = z2 * c3w[l];
  for (int off = 32; off > 0; off >>= 1) prod += __shfl_down(prod, off);
  if (l == 0) out[g] = prod + c3b[0];
}

extern "C" void kernel_launch(void* const* d_in, const int* in_sizes, int n_in,
                              void* d_out, int out_size, void* d_ws, size_t ws_size,
                              hipStream_t stream){
  const float* x    = (const float*)d_in[0];
  const int* eA     = (const int*)d_in[1];
  const int* eC     = (const int*)d_in[2];
  const int* eP     = (const int*)d_in[3];
  const int* batch  = (const int*)d_in[4];
  const float* bn_w = (const float*)d_in[6];
  const float* bn_b = (const float*)d_in[7];
  const float* WA   = (const float*)d_in[8];
  const float* asA  = (const float*)d_in[9];
  const float* adA  = (const float*)d_in[10];
  const float* bA   = (const float*)d_in[11];
  const float* WC   = (const float*)d_in[12];
  const float* asC  = (const float*)d_in[13];
  const float* adC  = (const float*)d_in[14];
  const float* bC   = (const float*)d_in[15];
  const float* WP   = (const float*)d_in[16];
  const float* asP  = (const float*)d_in[17];
  const float* adP  = (const float*)d_in[18];
  const float* bP   = (const float*)d_in[19];
  const float* g1w  = (const float*)d_in[20];
  const float* g1b  = (const float*)d_in[21];
  const float* g2w  = (const float*)d_in[22];
  const float* g2b  = (const float*)d_in[23];
  const float* c1w  = (const float*)d_in[24];
  const float* c1b  = (const float*)d_in[25];
  const float* c2w  = (const float*)d_in[26];
  const float* c2b  = (const float*)d_in[27];
  const float* c3w  = (const float*)d_in[28];
  const float* c3b  = (const float*)d_in[29];
  float* out = (float*)d_out;

  char* wptr = (char*)d_ws;
  auto alloc = [&](size_t bytes) -> void* {
    void* p = (void*)wptr;
    wptr += (bytes + 255) & ~(size_t)255;
    return p;
  };
  float*    sums    = (float*)   alloc((size_t)NF * 4);
  float*    sumsq   = (float*)   alloc((size_t)NF * 4);
  size_t zbytes = (size_t)(wptr - (char*)sums);
  int*      gcounts = (int*)     alloc((size_t)SCAN_N * 4);
  int*      gscan   = (int*)     alloc((size_t)SCAN_N * 4);
  int*      offsets = (int*)     alloc(((size_t)N3 + 1) * 4);
  __half*   WpT     = (__half*)  alloc((size_t)NOUT3 * NF * 2);
  float*    bp      = (float*)   alloc((size_t)NOUT3 * 4);
  __half*   h16     = (__half*)  alloc((size_t)N_NODES * NOUT3 * 2);
  float*    a_src   = (float*)   alloc((size_t)N3 * 2 * 4);
  float*    a_dst   = (float*)   alloc((size_t)N3 * 2 * 4);
  int*      packed  = (int*)     alloc((size_t)NE3 * 4);
  int*      entries = (int*)     alloc((size_t)NE3 * 4);
  unsigned* pooled  = (unsigned*)alloc((size_t)3 * NG * NHC * 4);
  unsigned* gpart   = (unsigned*)alloc((size_t)ATT_NB * 6 * 4);
  unsigned* amax    = (unsigned*)alloc((size_t)64 * 4);
  int*      bsum    = (int*)     alloc((size_t)512 * 4);
  int*      scrtot  = (int*)     alloc((size_t)64 * 4);

  hipMemsetAsync(sums, 0, zbytes, stream);
  k_init_pooled<<<(3 * NG * NHC + 255) / 256, 256, 0, stream>>>(pooled);
  k_pre<<<STATS_NB + NB1, 256, 0, stream>>>(x, sums, sumsq, eA, eC, eP, gcounts);
  k_prep2<<<NOUT3, 256, 0, stream>>>(sums, sumsq, bn_w, bn_b, WA, WC, WP, WpT, bp);
  int nb_sc = (SCAN_N + 2047) / 2048;   // 293
  k_scan1<<<nb_sc, 256, 0, stream>>>(gcounts, gscan, bsum, SCAN_N);
  k_scan2<<<1, 512, 0, stream>>>(bsum, scrtot, nb_sc);
  k_scan3<<<nb_sc, 256, 0, stream>>>(gscan, bsum, SCAN_N);
  k_fused<<<GEMM_NB + NB1, 256, 0, stream>>>(x, WpT, bp, h16, eA, eC, eP, gscan, packed);
  k_att<<<ATT_NB, 256, 0, stream>>>(h16, asA, adA, asC, adC, asP, adP, a_src, a_dst, gpart);
  k_amax<<<1, 256, 0, stream>>>(gpart, amax);
  k_build<<<NBUCK, 256, 0, stream>>>(gscan, packed, entries, offsets);
  k_gather<<<N3 / 16, 256, 0, stream>>>(entries, offsets, a_src, a_dst, amax, h16, bA, bC, bP, batch, pooled);
  k_head<<<NG, 64, 0, stream>>>(pooled, g1w, g1b, g2w, g2b, c1w, c1b, c2w, c2b, c3w, c3b, out);
}

// Round 6
// 377.452 us; speedup vs baseline: 1.5411x; 1.0837x over previous
//
#include <hip/hip_runtime.h>
#include <hip/hip_bf16.h>
#include <hip/hip_fp16.h>

#define N_NODES 100000
#define N_EDGES 1600000
#define ETOT    (N_EDGES + N_NODES)   // 1,700,000
#define NE3     (3 * ETOT)            // 5,100,000
#define N3      (3 * N_NODES)         // 300,000
#define NF      256
#define NG      512
#define NHC     64
#define NOUT3   192
#define BN_EPS  1e-5f

// bucket sort params: 512-node buckets
#define NBUCK   586                   // ceil(300000/512)
#define NB1     1024                  // level-1 blocks
#define EGRAIN  20
#define ECHUNK  (256 * EGRAIN)        // 5120
#define SCAN_N  (NBUCK * NB1)         // 600064
#define ATT_NB  (N3 * 16 / 256)       // 18750

typedef _Float16 f16x8 __attribute__((ext_vector_type(8)));
typedef float    f32x4 __attribute__((ext_vector_type(4)));

__device__ __forceinline__ unsigned fenc(float f){
  unsigned b = __float_as_uint(f);
  return (b & 0x80000000u) ? ~b : (b | 0x80000000u);
}
__device__ __forceinline__ float fdec(unsigned u){
  unsigned b = (u & 0x80000000u) ? (u & 0x7FFFFFFFu) : ~u;
  return __uint_as_float(b);
}
__device__ __forceinline__ float lrelu(float x){ return x > 0.f ? x : 0.2f * x; }
__device__ __forceinline__ float eluf(float x){ return x > 0.f ? x : (__expf(x) - 1.f); }

// ---------------- init pooled to encoded -inf ----------------
__global__ void k_init_pooled(unsigned* pooled){
  int i = blockIdx.x * 256 + threadIdx.x;
  if (i < 3 * NG * NHC) pooled[i] = 0x007FFFFFu;   // fenc(-inf)
}

// ---------------- fused: column stats of x + level-1 edge histogram ----------------
#define STATS_NB ((N_NODES + 127) / 128)    // 782
__global__ __launch_bounds__(256) void k_pre(const float* __restrict__ x,
                                             float* __restrict__ sums, float* __restrict__ sumsq,
                                             const int* __restrict__ eA, const int* __restrict__ eC,
                                             const int* __restrict__ eP,
                                             int* __restrict__ gcounts){
  int t = threadIdx.x;
  if (blockIdx.x < STATS_NB){
    int r0 = blockIdx.x * 128;
    int rmax = N_NODES - r0; if (rmax > 128) rmax = 128;
    float s = 0.f, q = 0.f;
    for (int r = 0; r < rmax; ++r){
      float v = x[(size_t)(r0 + r) * NF + t];
      s += v; q += v * v;
    }
    atomicAdd(&sums[t], s);
    atomicAdd(&sumsq[t], q);
    return;
  }
  __shared__ int hist[NBUCK];
  int bi = blockIdx.x - STATS_NB;
  for (int b = t; b < NBUCK; b += 256) hist[b] = 0;
  __syncthreads();
  int base = bi * ECHUNK + t;
#pragma unroll
  for (int k = 0; k < EGRAIN; ++k){
    int i = base + k * 256;
    if (i < NE3){
      int v = i / ETOT; int j = i - v * ETOT;
      const int* ei = (v == 0) ? eA : (v == 1) ? eC : eP;
      int d = (j < N_EDGES) ? ei[N_EDGES + j] : (j - N_EDGES);
      int vd = v * N_NODES + d;
      atomicAdd(&hist[vd >> 9], 1);
    }
  }
  __syncthreads();
  for (int b = t; b < NBUCK; b += 256) gcounts[b * NB1 + bi] = hist[b];
}

// ---------------- fold BN into W'^T (fp16, [192][256]) and bias b' ----------------
__global__ __launch_bounds__(256) void k_prep2(const float* __restrict__ sums, const float* __restrict__ sumsq,
                                               const float* __restrict__ bn_w, const float* __restrict__ bn_b,
                                               const float* __restrict__ WA, const float* __restrict__ WC,
                                               const float* __restrict__ WP,
                                               __half* __restrict__ WpT, float* __restrict__ bp){
  __shared__ float red[256];
  int o = blockIdx.x;                 // 0..191
  int v = o >> 6, oc = o & 63;
  const float* W = (v == 0) ? WA : (v == 1) ? WC : WP;
  int f = threadIdx.x;
  float mu  = sums[f]  * (1.f / N_NODES);
  float var = sumsq[f] * (1.f / N_NODES) - mu * mu;
  float sc  = bn_w[f] * rsqrtf(var + BN_EPS);
  float sh_ = bn_b[f] - mu * sc;
  float w = W[f * 64 + oc];
  WpT[(size_t)o * NF + f] = __float2half(w * sc);
  red[f] = sh_ * w;
  __syncthreads();
  for (int off = 128; off > 0; off >>= 1){
    if (f < off) red[f] += red[f + off];
    __syncthreads();
  }
  if (f == 0) bp[o] = red[0];
}

// ---------------- exclusive scan (grain 8, 3 phases) ----------------
__global__ __launch_bounds__(256) void k_scan1(const int* __restrict__ cnt, int* __restrict__ out,
                                               int* __restrict__ bsum, int n){
  __shared__ int sh[256];
  int t = threadIdx.x; int base = blockIdx.x * 2048 + t * 8;
  int v[8]; int s = 0;
#pragma unroll
  for (int i = 0; i < 8; ++i){ v[i] = (base + i < n) ? cnt[base + i] : 0; s += v[i]; }
  sh[t] = s; __syncthreads();
  for (int off = 1; off < 256; off <<= 1){
    int xv = (t >= off) ? sh[t - off] : 0;
    __syncthreads();
    sh[t] += xv;
    __syncthreads();
  }
  int p = sh[t] - s;
  if (t == 255) bsum[blockIdx.x] = sh[255];
#pragma unroll
  for (int i = 0; i < 8; ++i){ if (base + i < n) out[base + i] = p; p += v[i]; }
}

__global__ __launch_bounds__(512) void k_scan2(int* __restrict__ bsum, int* __restrict__ total_out, int nb){
  __shared__ int sh[512];
  int t = threadIdx.x;
  int o = (t < nb) ? bsum[t] : 0;
  sh[t] = o; __syncthreads();
  for (int off = 1; off < 512; off <<= 1){
    int xv = (t >= off) ? sh[t - off] : 0;
    __syncthreads();
    sh[t] += xv;
    __syncthreads();
  }
  if (t < nb) bsum[t] = sh[t] - o;
  if (t == nb - 1) total_out[0] = sh[t];
}

__global__ __launch_bounds__(256) void k_scan3(int* __restrict__ out, const int* __restrict__ bsum, int n){
  int add = bsum[blockIdx.x];
  int base = blockIdx.x * 2048 + threadIdx.x * 8;
#pragma unroll
  for (int i = 0; i < 8; ++i) if (base + i < n) out[base + i] += add;
}

// ---------------- fused: MFMA fp16 GEMM + level-1 scatter ----------------
#define GBM 64
#define GEMM_NB ((N_NODES + GBM - 1) / GBM)   // 1563
__global__ __launch_bounds__(256) void k_fused(const float* __restrict__ x,
                                               const __half* __restrict__ WpT, const float* __restrict__ bp,
                                               __half* __restrict__ h16,
                                               const int* __restrict__ eA, const int* __restrict__ eC,
                                               const int* __restrict__ eP,
                                               const int* __restrict__ gscan, int* __restrict__ packed){
  union U { _Float16 xs[64 * 256]; int pos[NBUCK]; };
  __shared__ U sm;
  int t = threadIdx.x;
  if (blockIdx.x >= GEMM_NB){
    // -------- scatter path: LDS cursors, no global atomics --------
    int bi = blockIdx.x - GEMM_NB;
    for (int b = t; b < NBUCK; b += 256) sm.pos[b] = gscan[b * NB1 + bi];
    __syncthreads();
    int base = bi * ECHUNK + t;
#pragma unroll
    for (int k = 0; k < EGRAIN; ++k){
      int i = base + k * 256;
      if (i < NE3){
        int v = i / ETOT; int j = i - v * ETOT;
        const int* ei = (v == 0) ? eA : (v == 1) ? eC : eP;
        int s, d;
        if (j < N_EDGES){ s = ei[j]; d = ei[N_EDGES + j]; } else { s = j - N_EDGES; d = s; }
        int vd = v * N_NODES + d;
        int p = atomicAdd(&sm.pos[vd >> 9], 1);
        packed[p] = s | ((vd & 511) << 17);
      }
    }
    return;
  }
  // -------- MFMA GEMM path: tile 64 x 192, K=256 --------
  int m0 = blockIdx.x * GBM;
#pragma unroll
  for (int k = 0; k < 8; ++k){
    int G = t + k * 256;            // granule id 0..2047 (16B each)
    int row = G >> 5, g = G & 31;
    int grow = m0 + row; if (grow >= N_NODES) grow = N_NODES - 1;
    const float4* src = (const float4*)(x + (size_t)grow * NF + ((g ^ (row & 7)) << 3));
    float4 lo = src[0], hi = src[1];
    f16x8 h;
    h[0]=(_Float16)lo.x; h[1]=(_Float16)lo.y; h[2]=(_Float16)lo.z; h[3]=(_Float16)lo.w;
    h[4]=(_Float16)hi.x; h[5]=(_Float16)hi.y; h[6]=(_Float16)hi.z; h[7]=(_Float16)hi.w;
    *(f16x8*)&sm.xs[(size_t)G << 3] = h;
  }
  __syncthreads();
  int lane = t & 63, w = t >> 6;
  int lr = lane & 15, lk = lane >> 4;
  int colb = w * 48;                  // wave's 48 output cols
  f32x4 acc[4][3];
#pragma unroll
  for (int mt = 0; mt < 4; ++mt)
#pragma unroll
    for (int ct = 0; ct < 3; ++ct) acc[mt][ct] = (f32x4){0.f, 0.f, 0.f, 0.f};
  float bpv[3];
#pragma unroll
  for (int ct = 0; ct < 3; ++ct) bpv[ct] = bp[colb + ct * 16 + lr];
#pragma unroll
  for (int kk = 0; kk < 8; ++kk){
    int khalf = kk * 32 + lk * 8;
    f16x8 av[4];
#pragma unroll
    for (int mt = 0; mt < 4; ++mt){
      int row = mt * 16 + lr;
      av[mt] = *(const f16x8*)&sm.xs[row * 256 + (khalf ^ ((row & 7) << 3))];
    }
    f16x8 bv[3];
#pragma unroll
    for (int ct = 0; ct < 3; ++ct){
      int col = colb + ct * 16 + lr;
      bv[ct] = *(const f16x8*)(const void*)(WpT + (size_t)col * NF + khalf);
    }
#pragma unroll
    for (int mt = 0; mt < 4; ++mt)
#pragma unroll
      for (int ct = 0; ct < 3; ++ct)
        acc[mt][ct] = __builtin_amdgcn_mfma_f32_16x16x32_f16(av[mt], bv[ct], acc[mt][ct], 0, 0, 0);
  }
  // epilogue: C layout col=lane&15, row=(lane>>4)*4+reg
#pragma unroll
  for (int mt = 0; mt < 4; ++mt){
#pragma unroll
    for (int r = 0; r < 4; ++r){
      int row = m0 + mt * 16 + lk * 4 + r;
      if (row < N_NODES){
#pragma unroll
        for (int ct = 0; ct < 3; ++ct)
          h16[(size_t)row * NOUT3 + colb + ct * 16 + lr] = __float2half(acc[mt][ct][r] + bpv[ct]);
      }
    }
  }
}

// ---------------- level-2: per-bucket exact CSR build (LDS only) ----------------
__global__ __launch_bounds__(256) void k_build(const int* __restrict__ gscan, const int* __restrict__ packed,
                                               int* __restrict__ entries, int* __restrict__ offsets){
  __shared__ int hist2[512];
  __shared__ int sh[256];
  int b = blockIdx.x, t = threadIdx.x;
  int base = gscan[b * NB1];
  int end  = (b == NBUCK - 1) ? NE3 : gscan[(b + 1) * NB1];
  hist2[t * 2] = 0; hist2[t * 2 + 1] = 0;
  __syncthreads();
  for (int i = base + t; i < end; i += 256)
    atomicAdd(&hist2[(packed[i] >> 17) & 511], 1);
  __syncthreads();
  int s0 = hist2[t * 2], s1 = hist2[t * 2 + 1];
  int tot = s0 + s1;
  sh[t] = tot; __syncthreads();
  for (int off = 1; off < 256; off <<= 1){
    int xv = (t >= off) ? sh[t - off] : 0;
    __syncthreads();
    sh[t] += xv;
    __syncthreads();
  }
  int p = sh[t] - tot;
  hist2[t * 2]     = p;
  hist2[t * 2 + 1] = p + s0;
  __syncthreads();
#pragma unroll
  for (int i = 0; i < 2; ++i){
    int vd = (b << 9) + t * 2 + i;
    if (vd < N3) offsets[vd] = base + hist2[t * 2 + i];
  }
  if (b == NBUCK - 1 && t == 0) offsets[N3] = NE3;
  __syncthreads();
  for (int i = base + t; i < end; i += 256){
    int pk = packed[i];
    int low = (pk >> 17) & 511;
    int pos = atomicAdd(&hist2[low], 1);
    entries[base + pos] = pk & 0x1FFFF;
  }
}

// ---------------- attention logits + per-block partial src-max (plain stores) ----------------
__global__ __launch_bounds__(256) void k_att(const __half* __restrict__ h16,
                                             const float* __restrict__ asA, const float* __restrict__ adA,
                                             const float* __restrict__ asC, const float* __restrict__ adC,
                                             const float* __restrict__ asP, const float* __restrict__ adP,
                                             float* __restrict__ a_src, float* __restrict__ a_dst,
                                             unsigned* __restrict__ gpart){
  __shared__ unsigned samax[6];
  int t = threadIdx.x;
  if (t < 6) samax[t] = 0u;
  __syncthreads();
  int gt = blockIdx.x * 256 + t;
  int g = gt >> 4; int lid = gt & 15;          // grid exact: g < N3 always
  int v = g / N_NODES; int n = g - v * N_NODES;
  const float* As = (v == 0) ? asA : (v == 1) ? asC : asP;
  const float* Ad = (v == 0) ? adA : (v == 1) ? adC : adP;
  const __half2* hp = (const __half2*)(h16 + (size_t)n * NOUT3 + v * 64 + lid * 4);
  float2 fa = __half22float2(hp[0]);
  float2 fb = __half22float2(hp[1]);
  float4 s4 = *(const float4*)(As + lid * 4);
  float4 d4 = *(const float4*)(Ad + lid * 4);
  float rs = fa.x*s4.x + fa.y*s4.y + fb.x*s4.z + fb.y*s4.w;
  float rd = fa.x*d4.x + fa.y*d4.y + fb.x*d4.z + fb.y*d4.w;
  rs += __shfl_xor(rs, 1); rd += __shfl_xor(rd, 1);
  rs += __shfl_xor(rs, 2); rd += __shfl_xor(rd, 2);
  rs += __shfl_xor(rs, 4); rd += __shfl_xor(rd, 4);
  if ((lid & 7) == 0){
    int h = lid >> 3;
    a_src[g * 2 + h] = rs;
    a_dst[g * 2 + h] = rd;
    atomicMax(&samax[v * 2 + h], fenc(rs));
  }
  __syncthreads();
  if (t < 6) gpart[blockIdx.x * 6 + t] = samax[t];   // plain store, no global atomic
}

// ---------------- reduce 18750x6 partials -> amax[6] ----------------
__global__ __launch_bounds__(256) void k_amax(const unsigned* __restrict__ gpart, unsigned* __restrict__ amax){
  __shared__ unsigned sm[6];
  int t = threadIdx.x;
  if (t < 6) sm[t] = 0u;
  __syncthreads();
  unsigned m[6] = {0u, 0u, 0u, 0u, 0u, 0u};
  for (int bi = t; bi < ATT_NB; bi += 256){
    const unsigned* p = gpart + (size_t)bi * 6;
#pragma unroll
    for (int k = 0; k < 6; ++k) m[k] = max(m[k], p[k]);
  }
#pragma unroll
  for (int k = 0; k < 6; ++k) atomicMax(&sm[k], m[k]);
  __syncthreads();
  if (t < 6) amax[t] = sm[t];
}

// ---------------- gather: chunk-16 parallel softmax + shfl-broadcast aggregate ----------------
__global__ __launch_bounds__(256) void k_gather(const int* __restrict__ entries, const int* __restrict__ offsets,
                                                const float* __restrict__ a_src, const float* __restrict__ a_dst,
                                                const unsigned* __restrict__ amax,
                                                const __half* __restrict__ h16,
                                                const float* __restrict__ bA, const float* __restrict__ bC,
                                                const float* __restrict__ bP,
                                                const int* __restrict__ batch, unsigned* __restrict__ pooled){
  __shared__ unsigned red[64];
  __shared__ int kmin, kmax;
  int t = threadIdx.x;
  if (t == 0){ kmin = 0x7FFFFFFF; kmax = -1; }
  if (t < 64) red[t] = 0u;
  __syncthreads();
  int grp = t >> 4;
  int lid = t & 15;
  int g = blockIdx.x * 16 + grp;        // grid exact
  int v = g / N_NODES; int n = g - v * N_NODES;
  int vN = v * N_NODES;
  float ad0 = a_dst[g*2+0], ad1 = a_dst[g*2+1];
  float m0 = lrelu(fdec(amax[v*2+0]) + ad0);   // >= max edge logit for this dst
  float m1 = lrelu(fdec(amax[v*2+1]) + ad1);
  int beg = offsets[g], end = offsets[g+1];
  int len = end - beg;
  float ax = 0.f, ay = 0.f, az = 0.f, aw = 0.f;
  float den0 = 0.f, den1 = 0.f;
  const __half* hbase = h16 + v * 64 + lid * 4;   // lane's 8B column slice
  for (int c0 = 0; c0 < len; c0 += 16){
    int nc = len - c0; if (nc > 16) nc = 16;
    // phase A: one edge per lane — coalesced entries read, single exp pair
    int s_ = 0; float p0 = 0.f, p1 = 0.f;
    if (lid < nc){
      s_ = entries[beg + c0 + lid];
      float2 ap = *(const float2*)(a_src + (size_t)(vN + s_) * 2);
      p0 = __expf(lrelu(ap.x + ad0) - m0);
      p1 = __expf(lrelu(ap.y + ad1) - m1);
    }
    den0 += p0; den1 += p1;
    // phase B: broadcast + aggregate, 4-deep load pipeline
    for (int k = 0; k < nc; k += 4){
      uint2 r[4]; float pav[4], pbv[4];
#pragma unroll
      for (int j = 0; j < 4; ++j){
        int kk = k + j;
        int sk = __shfl(s_, kk, 16);              // lanes >= nc hold s_=0 -> valid row 0
        r[j] = *(const uint2*)(hbase + (size_t)sk * NOUT3);
        pav[j] = __shfl(p0, kk, 16);
        pbv[j] = __shfl(p1, kk, 16);
      }
#pragma unroll
      for (int j = 0; j < 4; ++j){
        int kk = k + j;
        if (kk < nc){
          float ph = (lid < 8) ? pav[j] : pbv[j];
          float2 fa2 = __half22float2(*(__half2*)&r[j].x);
          float2 fb2 = __half22float2(*(__half2*)&r[j].y);
          ax += ph * fa2.x; ay += ph * fa2.y; az += ph * fb2.x; aw += ph * fb2.y;
        }
      }
    }
  }
  // reduce den across the 16 lanes (each lane summed its own edges)
#pragma unroll
  for (int msk = 1; msk < 16; msk <<= 1){
    den0 += __shfl_xor(den0, msk);
    den1 += __shfl_xor(den1, msk);
  }
  float den = ((lid < 8) ? den0 : den1) + 1e-16f;
  const float* bias = (v == 0) ? bA : (v == 1) ? bC : bP;
  float4 b4 = *(const float4*)(bias + lid * 4);
  unsigned e0u = fenc(eluf(ax / den + b4.x));
  unsigned e1u = fenc(eluf(ay / den + b4.y));
  unsigned e2u = fenc(eluf(az / den + b4.z));
  unsigned e3u = fenc(eluf(aw / den + b4.w));
  int key = v * NG + batch[n];
  if (lid == 0){ atomicMin(&kmin, key); atomicMax(&kmax, key); }
  atomicMax(&red[lid*4+0], e0u); atomicMax(&red[lid*4+1], e1u);
  atomicMax(&red[lid*4+2], e2u); atomicMax(&red[lid*4+3], e3u);
  __syncthreads();
  if (kmin == kmax){
    if (t < 64) atomicMax(&pooled[(size_t)kmin * 64 + t], red[t]);
  } else {
    unsigned* pp = pooled + (size_t)key * 64 + lid * 4;
    atomicMax(pp+0, e0u); atomicMax(pp+1, e1u); atomicMax(pp+2, e2u); atomicMax(pp+3, e3u);
  }
}

// ---------------- head MLP: one wave per graph ----------------
__global__ __launch_bounds__(64) void k_head(const unsigned* __restrict__ pooled,
                                             const float* __restrict__ g1w, const float* __restrict__ g1b,
                                             const float* __restrict__ g2w, const float* __restrict__ g2b,
                                             const float* __restrict__ c1w, const float* __restrict__ c1b,
                                             const float* __restrict__ c2w, const float* __restrict__ c2b,
                                             const float* __restrict__ c3w, const float* __restrict__ c3b,
                                             float* __restrict__ out){
  __shared__ float s1[64];
  __shared__ float s2[128];
  __shared__ float sw[3];
  int g = blockIdx.x, l = threadIdx.x;
  float ha = fdec(pooled[(size_t)g * 64 + l]);
  float hc = fdec(pooled[(size_t)(NG + g) * 64 + l]);
  float hp = fdec(pooled[(size_t)(2 * NG + g) * 64 + l]);
  s1[l] = (ha + hc + hp) * (1.f / 3.f);
  __syncthreads();
  float r1 = 0.f;
  if (l < 32){
    r1 = g1b[l];
    for (int i = 0; i < 64; ++i) r1 += s1[i] * g1w[i * 32 + l];
    r1 = fmaxf(r1, 0.f);
  }
  __syncthreads();
  if (l < 32) s2[l] = r1;
  __syncthreads();
  if (l < 3){
    float tv = g2b[l];
    for (int i = 0; i < 32; ++i) tv += s2[i] * g2w[i * 3 + l];
    sw[l] = tv;
  }
  __syncthreads();
  float t0 = sw[0], t1 = sw[1], t2 = sw[2];
  float mx = fmaxf(t0, fmaxf(t1, t2));
  float w0 = __expf(t0 - mx), w1 = __expf(t1 - mx), w2 = __expf(t2 - mx);
  float wsum = w0 + w1 + w2;
  float fused = (w0 * ha + w1 * hc + w2 * hp) / wsum;
  __syncthreads();
  s1[l] = fused;
  __syncthreads();
  float za = c1b[l], zb = c1b[64 + l];
  for (int i = 0; i < 64; ++i){
    float f = s1[i];
    za += f * c1w[i * 128 + l];
    zb += f * c1w[i * 128 + 64 + l];
  }
  za = fmaxf(za, 0.f); zb = fmaxf(zb, 0.f);
  s2[l] = za; s2[64 + l] = zb;
  __syncthreads();
  float z2 = c2b[l];
  for (int i = 0; i < 128; ++i) z2 += s2[i] * c2w[i * 64 + l];
  z2 = fmaxf(z2, 0.f);
  float prod = z2 * c3w[l];
  for (int off = 32; off > 0; off >>= 1) prod += __shfl_down(prod, off);
  if (l == 0) out[g] = prod + c3b[0];
}

extern "C" void kernel_launch(void* const* d_in, const int* in_sizes, int n_in,
                              void* d_out, int out_size, void* d_ws, size_t ws_size,
                              hipStream_t stream){
  const float* x    = (const float*)d_in[0];
  const int* eA     = (const int*)d_in[1];
  const int* eC     = (const int*)d_in[2];
  const int* eP     = (const int*)d_in[3];
  const int* batch  = (const int*)d_in[4];
  const float* bn_w = (const float*)d_in[6];
  const float* bn_b = (const float*)d_in[7];
  const float* WA   = (const float*)d_in[8];
  const float* asA  = (const float*)d_in[9];
  const float* adA  = (const float*)d_in[10];
  const float* bA   = (const float*)d_in[11];
  const float* WC   = (const float*)d_in[12];
  const float* asC  = (const float*)d_in[13];
  const float* adC  = (const float*)d_in[14];
  const float* bC   = (const float*)d_in[15];
  const float* WP   = (const float*)d_in[16];
  const float* asP  = (const float*)d_in[17];
  const float* adP  = (const float*)d_in[18];
  const float* bP   = (const float*)d_in[19];
  const float* g1w  = (const float*)d_in[20];
  const float* g1b  = (const float*)d_in[21];
  const float* g2w  = (const float*)d_in[22];
  const float* g2b  = (const float*)d_in[23];
  const float* c1w  = (const float*)d_in[24];
  const float* c1b  = (const float*)d_in[25];
  const float* c2w  = (const float*)d_in[26];
  const float* c2b  = (const float*)d_in[27];
  const float* c3w  = (const float*)d_in[28];
  const float* c3b  = (const float*)d_in[29];
  float* out = (float*)d_out;

  char* wptr = (char*)d_ws;
  auto alloc = [&](size_t bytes) -> void* {
    void* p = (void*)wptr;
    wptr += (bytes + 255) & ~(size_t)255;
    return p;
  };
  float*    sums    = (float*)   alloc((size_t)NF * 4);
  float*    sumsq   = (float*)   alloc((size_t)NF * 4);
  size_t zbytes = (size_t)(wptr - (char*)sums);
  int*      gcounts = (int*)     alloc((size_t)SCAN_N * 4);
  int*      gscan   = (int*)     alloc((size_t)SCAN_N * 4);
  int*      offsets = (int*)     alloc(((size_t)N3 + 1) * 4);
  __half*   WpT     = (__half*)  alloc((size_t)NOUT3 * NF * 2);
  float*    bp      = (float*)   alloc((size_t)NOUT3 * 4);
  __half*   h16     = (__half*)  alloc((size_t)N_NODES * NOUT3 * 2);
  float*    a_src   = (float*)   alloc((size_t)N3 * 2 * 4);
  float*    a_dst   = (float*)   alloc((size_t)N3 * 2 * 4);
  int*      packed  = (int*)     alloc((size_t)NE3 * 4);
  int*      entries = (int*)     alloc((size_t)NE3 * 4);
  unsigned* pooled  = (unsigned*)alloc((size_t)3 * NG * NHC * 4);
  unsigned* gpart   = (unsigned*)alloc((size_t)ATT_NB * 6 * 4);
  unsigned* amax    = (unsigned*)alloc((size_t)64 * 4);
  int*      bsum    = (int*)     alloc((size_t)512 * 4);
  int*      scrtot  = (int*)     alloc((size_t)64 * 4);

  hipMemsetAsync(sums, 0, zbytes, stream);
  k_init_pooled<<<(3 * NG * NHC + 255) / 256, 256, 0, stream>>>(pooled);
  k_pre<<<STATS_NB + NB1, 256, 0, stream>>>(x, sums, sumsq, eA, eC, eP, gcounts);
  k_prep2<<<NOUT3, 256, 0, stream>>>(sums, sumsq, bn_w, bn_b, WA, WC, WP, WpT, bp);
  int nb_sc = (SCAN_N + 2047) / 2048;   // 293
  k_scan1<<<nb_sc, 256, 0, stream>>>(gcounts, gscan, bsum, SCAN_N);
  k_scan2<<<1, 512, 0, stream>>>(bsum, scrtot, nb_sc);
  k_scan3<<<nb_sc, 256, 0, stream>>>(gscan, bsum, SCAN_N);
  k_fused<<<GEMM_NB + NB1, 256, 0, stream>>>(x, WpT, bp, h16, eA, eC, eP, gscan, packed);
  k_att<<<ATT_NB, 256, 0, stream>>>(h16, asA, adA, asC, adC, asP, adP, a_src, a_dst, gpart);
  k_amax<<<1, 256, 0, stream>>>(gpart, amax);
  k_build<<<NBUCK, 256, 0, stream>>>(gscan, packed, entries, offsets);
  k_gather<<<N3 / 16, 256, 0, stream>>>(entries, offsets, a_src, a_dst, amax, h16, bA, bC, bP, batch, pooled);
  k_head<<<NG, 64, 0, stream>>>(pooled, g1w, g1b, g2w, g2b, c1w, c1b, c2w, c2b, c3w, c3b, out);
}